// Round 1
// baseline (456.178 us; speedup 1.0000x reference)
//
#include <hip/hip_runtime.h>

#define NN 8192
#define FIN 512
#define FOUT 64
#define LRELU_ALPHA 0.2f
#define MASK_VALF -9000000000000000.0f

typedef __attribute__((ext_vector_type(4))) float f32x4;
typedef __attribute__((ext_vector_type(4))) int i32x4;
typedef __attribute__((ext_vector_type(8))) __bf16 bf16x8;

// Kernel A: Wh = x@W (fp32), s1 = Wh@a1, s2 = Wh@a2 (fp32), WhbT = bf16 transpose (64 x 8192).
// Thread t handles (row = gid/16, cols cg*4..cg*4+3), cg = gid&15 == lane&15.
__global__ __launch_bounds__(256) void gat_wh(
    const float* __restrict__ x, const float* __restrict__ W,
    const float* __restrict__ A,
    __bf16* __restrict__ WhbT, float* __restrict__ s1, float* __restrict__ s2)
{
    const int gid = blockIdx.x * 256 + threadIdx.x;
    const int row = gid >> 4;
    const int cg  = gid & 15;

    f32x4 acc = {0.f, 0.f, 0.f, 0.f};
    const float* xrow = x + (size_t)row * FIN;
    const float* wcol = W + cg * 4;

    #pragma unroll 2
    for (int k = 0; k < FIN; k += 4) {
        f32x4 xv = *reinterpret_cast<const f32x4*>(xrow + k);
        #pragma unroll
        for (int u = 0; u < 4; ++u) {
            f32x4 wv = *reinterpret_cast<const f32x4*>(wcol + (size_t)(k + u) * FOUT);
            acc += xv[u] * wv;
        }
    }

    f32x4 a1v = *reinterpret_cast<const f32x4*>(A + cg * 4);
    f32x4 a2v = *reinterpret_cast<const f32x4*>(A + FOUT + cg * 4);
    float s1p = acc[0]*a1v[0] + acc[1]*a1v[1] + acc[2]*a1v[2] + acc[3]*a1v[3];
    float s2p = acc[0]*a2v[0] + acc[1]*a2v[1] + acc[2]*a2v[2] + acc[3]*a2v[3];
    #pragma unroll
    for (int off = 1; off < 16; off <<= 1) {
        s1p += __shfl_xor(s1p, off);
        s2p += __shfl_xor(s2p, off);
    }
    if (cg == 0) { s1[row] = s1p; s2[row] = s2p; }

    #pragma unroll
    for (int u = 0; u < 4; ++u)
        WhbT[(size_t)(cg * 4 + u) * NN + row] = (__bf16)acc[u];
}

// Kernel B: fused masked-softmax attention, flash-style. Block = 16 rows, 4 waves,
// each wave owns a 2048-col strip with private online-softmax state; LDS merge at end.
// adj read exactly once (268 MB -> the HBM roofline).
__global__ __launch_bounds__(256) void gat_attn(
    const int* __restrict__ adj, const __bf16* __restrict__ WhbT,
    const float* __restrict__ s1g, const float* __restrict__ s2g,
    const float* __restrict__ bias, float* __restrict__ out)
{
    __shared__ float s2_lds[NN];
    __shared__ float om[4][16];
    __shared__ float ol[4][16];
    __shared__ float oacc[4][16][FOUT];

    const int tid  = threadIdx.x;
    const int w    = tid >> 6;
    const int lane = tid & 63;
    const int r    = lane & 15;   // MFMA A-layout row / B-layout col
    const int q    = lane >> 4;   // quad: k-chunk q*8..q*8+7
    const int row0 = blockIdx.x * 16;

    for (int i = tid; i < NN / 4; i += 256)
        reinterpret_cast<f32x4*>(s2_lds)[i] = reinterpret_cast<const f32x4*>(s2g)[i];
    __syncthreads();

    const float s1r = s1g[row0 + r];

    float m = -INFINITY;
    float l = 0.0f;
    f32x4 acc0 = {0,0,0,0}, acc1 = {0,0,0,0}, acc2 = {0,0,0,0}, acc3 = {0,0,0,0};

    const int*    adjp = adj + (size_t)(row0 + r) * NN + q * 8;
    const __bf16* wp   = WhbT + q * 8;

    for (int it = 0; it < 64; ++it) {
        const int j0 = (w << 11) + (it << 5);

        i32x4 av0 = *reinterpret_cast<const i32x4*>(adjp + j0);
        i32x4 av1 = *reinterpret_cast<const i32x4*>(adjp + j0 + 4);
        bf16x8 b0 = *reinterpret_cast<const bf16x8*>(wp + (size_t)(0 * 16 + r) * NN + j0);
        bf16x8 b1 = *reinterpret_cast<const bf16x8*>(wp + (size_t)(1 * 16 + r) * NN + j0);
        bf16x8 b2 = *reinterpret_cast<const bf16x8*>(wp + (size_t)(2 * 16 + r) * NN + j0);
        bf16x8 b3 = *reinterpret_cast<const bf16x8*>(wp + (size_t)(3 * 16 + r) * NN + j0);
        f32x4 s2a = *reinterpret_cast<const f32x4*>(s2_lds + j0 + q * 8);
        f32x4 s2b = *reinterpret_cast<const f32x4*>(s2_lds + j0 + q * 8 + 4);

        float ev[8];
        #pragma unroll
        for (int i = 0; i < 4; ++i) {
            float t0 = s1r + s2a[i];
            float e0 = fmaxf(t0, LRELU_ALPHA * t0);       // leaky_relu, slope<1
            ev[i] = (av0[i] > 0) ? e0 : MASK_VALF;
            float t1 = s1r + s2b[i];
            float e1 = fmaxf(t1, LRELU_ALPHA * t1);
            ev[i + 4] = (av1[i] > 0) ? e1 : MASK_VALF;
        }

        float tmax = ev[0];
        #pragma unroll
        for (int i = 1; i < 8; ++i) tmax = fmaxf(tmax, ev[i]);
        tmax = fmaxf(tmax, __shfl_xor(tmax, 16));
        tmax = fmaxf(tmax, __shfl_xor(tmax, 32));

        const float mnew  = fmaxf(m, tmax);
        const float alpha = __expf(m - mnew);             // first iter: exp(-inf)=0
        m = mnew;

        float psum = 0.f;
        bf16x8 af;
        #pragma unroll
        for (int i = 0; i < 8; ++i) {
            float p = __expf(ev[i] - mnew);               // all-masked tile: exp(0)=1 (matches ref)
            psum += p;
            af[i] = (__bf16)p;
        }
        psum += __shfl_xor(psum, 16);
        psum += __shfl_xor(psum, 32);
        l = l * alpha + psum;

        // rescale accumulators: C-layout row = q*4+reg; alpha for row rr held by lane rr
        const float ar0 = __shfl(alpha, q * 4 + 0);
        const float ar1 = __shfl(alpha, q * 4 + 1);
        const float ar2 = __shfl(alpha, q * 4 + 2);
        const float ar3 = __shfl(alpha, q * 4 + 3);
        f32x4 av = {ar0, ar1, ar2, ar3};
        acc0 *= av; acc1 *= av; acc2 *= av; acc3 *= av;

        acc0 = __builtin_amdgcn_mfma_f32_16x16x32_bf16(af, b0, acc0, 0, 0, 0);
        acc1 = __builtin_amdgcn_mfma_f32_16x16x32_bf16(af, b1, acc1, 0, 0, 0);
        acc2 = __builtin_amdgcn_mfma_f32_16x16x32_bf16(af, b2, acc2, 0, 0, 0);
        acc3 = __builtin_amdgcn_mfma_f32_16x16x32_bf16(af, b3, acc3, 0, 0, 0);
    }

    // cross-wave merge via LDS (log-sum-exp)
    if (lane < 16) { om[w][lane] = m; ol[w][lane] = l; }
    #pragma unroll
    for (int reg = 0; reg < 4; ++reg) {
        oacc[w][q * 4 + reg][0 * 16 + r] = acc0[reg];
        oacc[w][q * 4 + reg][1 * 16 + r] = acc1[reg];
        oacc[w][q * 4 + reg][2 * 16 + r] = acc2[reg];
        oacc[w][q * 4 + reg][3 * 16 + r] = acc3[reg];
    }
    __syncthreads();

    for (int o = tid; o < 16 * FOUT; o += 256) {
        const int rr = o >> 6;
        const int f  = o & 63;
        const float M = fmaxf(fmaxf(om[0][rr], om[1][rr]), fmaxf(om[2][rr], om[3][rr]));
        float L = 0.f, O = 0.f;
        #pragma unroll
        for (int w2 = 0; w2 < 4; ++w2) {
            const float sc = __expf(om[w2][rr] - M);
            L += sc * ol[w2][rr];
            O += sc * oacc[w2][rr][f];
        }
        out[(size_t)(row0 + rr) * FOUT + f] = O / L + bias[f];
    }
}

extern "C" void kernel_launch(void* const* d_in, const int* in_sizes, int n_in,
                              void* d_out, int out_size, void* d_ws, size_t ws_size,
                              hipStream_t stream)
{
    const float* x    = (const float*)d_in[0];
    const int*   adj  = (const int*)d_in[1];
    const float* W    = (const float*)d_in[2];
    const float* bias = (const float*)d_in[3];
    const float* A    = (const float*)d_in[4];
    float* out = (float*)d_out;

    // workspace: WhbT (1 MB) | s1 (32 KB) | s2 (32 KB)
    char* ws = (char*)d_ws;
    __bf16* WhbT = (__bf16*)ws;
    float*  s1   = (float*)(ws + (size_t)FOUT * NN * sizeof(__bf16));
    float*  s2   = s1 + NN;

    gat_wh<<<dim3(NN * 16 / 256), dim3(256), 0, stream>>>(x, W, A, WhbT, s1, s2);
    gat_attn<<<dim3(NN / 16), dim3(256), 0, stream>>>(adj, WhbT, s1, s2, bias, out);
}